// Round 11
// baseline (10.643 us; speedup 1.0000x reference)
//
#include <hip/hip_runtime.h>

#define Bb 128
#define Cc 400
#define Ll 100
#define Pp 16
#define KP 128       // K padded to 4 MFMA k-steps
#define WS 136       // wT row stride (elements): 272B -> 2-way conflict max

typedef __attribute__((ext_vector_type(8))) short short8;  // 8 bf16 (4 VGPR)
typedef __attribute__((ext_vector_type(4))) float f32x4;
typedef unsigned int u32;
typedef const __attribute__((address_space(1))) u32* gas_p;
typedef __attribute__((address_space(3))) u32* las_p;

// fp32 -> bf16, round-to-nearest-even, branchless
static __device__ __forceinline__ unsigned short f2bf(float f) {
  unsigned int u = __float_as_uint(f);
  u += 0x7fffu + ((u >> 16) & 1u);
  return (unsigned short)(u >> 16);
}

// ---------------------------------------------------------------------------
// R10 structure + support-windowed x staging.
//
// w[i][l] != 0 only for i in [s,e], so only x columns [c0,c1) =
// [s&~3, (e+4)&~3) are needed (avg ~36 of 100): per-row DMA with lane<nv
// exec mask cuts FETCH ~2x. Un-staged LDS is garbage -> phase 2 bit-selects
// zero (v_cndmask, no FP touch, no branches) for k outside [c0,c1).
//
// Per block (batch b, 8 tiles of 16 ch): (0) windowed global_load_lds DMA;
// (1) closed-form w -> bf16 wT[l][i] in LDS (flat); (2) __syncthreads
// (drains vmcnt); (3) A-frags from x_lds, B-frags from wT,
// 4 x mfma_f32_16x16x32_bf16, coalesced store.
//
// Fragment layouts (gfx950, §3, m89-verified): A: row=lane&15, k=8*(lane>>4)+j;
// B: col=lane&15 (wT row l), same k; D: col=lane&15, row=4*(lane>>4)+v.
//
// Weight closed form (per b,l): q_j = 16*s + d*l + j (j in [0,d)),
// t=(min(q+8,1592)-8)/16, i0=min(floor(t),98), fr=t-i0;
// w[i] = [sum_{i0==i}(1-fr) + sum_{i0==i-1}(fr)] / max(d,1);
// contiguous q-ranges -> triangular-number sums.
// ---------------------------------------------------------------------------
__global__ __launch_bounds__(512) void TemporalPooling_mfma_kernel(
    const float* __restrict__ x, const int* __restrict__ seg,
    float* __restrict__ out) {
  __shared__ unsigned short wT[Pp * WS];     // [l][i] bf16, 4352 B
  __shared__ float xls[8][16 * Ll];          // per-wave 16x100 f32, 51.2 KiB

  const int b    = blockIdx.y;
  const int tid  = threadIdx.x;
  const int wave = tid >> 6;                 // 0..7
  const int lane = tid & 63;
  const int arow = lane & 15;
  const int g    = lane >> 4;
  const int tile = blockIdx.x * 8 + wave;    // 0..31; 25 real
  const bool active = (tile < Cc / 16);

  const int s = seg[2 * b];
  const int e = seg[2 * b + 1];
  const int d = e - s;
  const float inv = 1.0f / (float)max(d, 1);

  // support-aligned column window [c0, c1), 16B-aligned, c1 <= 100
  const int c0 = s & ~3;
  const int c1 = (e + 4) & ~3;
  const int nv = (c1 - c0) >> 2;             // 16B chunks per row, 1..25

  // ---- 0: windowed async DMA x tile -> LDS (16 per-row transfers) ----
  if (active && lane < nv) {
    const float* gsrc = x + ((size_t)b * Cc + tile * 16) * Ll + c0;
    float* lbase = &xls[wave][c0];
#pragma unroll
    for (int r = 0; r < 16; ++r) {
      __builtin_amdgcn_global_load_lds((gas_p)(gsrc + r * Ll + lane * 4),
                                       (las_p)(lbase + r * Ll), 16, 0, 0);
    }
  }

  // ---- 1: weights into LDS (flat closed form, 4 entries/thread) ----
  for (int idx = tid; idx < Pp * KP; idx += 512) {
    const int i = idx >> 4;    // 0..127 (>=100 -> 0 naturally)
    const int l = idx & 15;

    const int a  = 16 * s + d * l;
    const int ad = a + d;

    float sum = 0.0f;
    const int base1 = 16 * i;
    {  // i0 == i : q in [16i,16i+16) ∩ [a,ad) ∩ [0,1584)
      const int lo = max(base1, a);
      const int hi = min(min(base1 + 16, ad), 1584);
      const int n = hi - lo;
      if (n > 0) {
        const int sq = (hi * (hi - 1) - lo * (lo - 1)) >> 1;
        sum += (float)n - (float)(sq - n * base1) * 0.0625f;
      }
    }
    {  // i0 == i-1 : q in [16(i-1),16i) ∩ [a,ad) ∩ [0,1584)
      const int base2 = base1 - 16;
      const int lo = max(base2, a);
      const int hi = min(min(base1, ad), 1584);
      const int n = hi - lo;
      if (n > 0) {
        const int sq = (hi * (hi - 1) - lo * (lo - 1)) >> 1;
        sum += (float)(sq - n * base2) * 0.0625f;
      }
    }
    if (i == Ll - 1) {  // clip tail (never fires for e<=99; safety)
      const int nclip = ad - max(a, 1584);
      if (nclip > 0) sum += (float)nclip;
    }

    wT[l * WS + i] = f2bf(sum * inv);
  }
  __syncthreads();   // also drains vmcnt(0): DMA complete

  if (!active) return;

  // ---- 2: A from x_lds (window-masked), B from wT, 4 MFMA ----
  const float* xrow = &xls[wave][arow * Ll];
  const unsigned span = (unsigned)(c1 - c0);

  f32x4 acc = {0.f, 0.f, 0.f, 0.f};
#pragma unroll
  for (int t = 0; t < 4; ++t) {
    const int k0 = t * 32 + g * 8;
    float xf[8];
    if (t < 3) {                                  // k0..k0+7 <= 95: LDS in-bounds
      const float4 v0 = *(const float4*)(xrow + k0);
      const float4 v1 = *(const float4*)(xrow + k0 + 4);
      xf[0] = v0.x; xf[1] = v0.y; xf[2] = v0.z; xf[3] = v0.w;
      xf[4] = v1.x; xf[5] = v1.y; xf[6] = v1.z; xf[7] = v1.w;
    } else {                                      // t=3: only g=0 has k<100
      xf[0] = xf[1] = xf[2] = xf[3] = 0.f;
      xf[4] = xf[5] = xf[6] = xf[7] = 0.f;
      if (g == 0) {
        const float4 v0 = *(const float4*)(xrow + 96);
        xf[0] = v0.x; xf[1] = v0.y; xf[2] = v0.z; xf[3] = v0.w;
      }
    }
    // bit-select zero outside the staged window (garbage must not reach FP)
#pragma unroll
    for (int j = 0; j < 8; ++j) {
      const int k = k0 + j;
      xf[j] = ((unsigned)(k - c0) < span) ? xf[j] : 0.0f;
    }

    short8 af;
#pragma unroll
    for (int j = 0; j < 8; ++j) af[j] = (short)f2bf(xf[j]);

    const short8 bf =
        *(const short8*)&wT[arow * WS + t * 32 + g * 8];  // ds_read_b128

    acc = __builtin_amdgcn_mfma_f32_16x16x32_bf16(af, bf, acc, 0, 0, 0);
  }

  // ---- epilogue: D[row=4g+v][col=arow] -> out[b, tile*16+4g+v, arow] ----
  float* obase = out + (((size_t)b * Cc + tile * 16 + g * 4) * Pp) + arow;
#pragma unroll
  for (int v = 0; v < 4; ++v) obase[v * Pp] = acc[v];
}

extern "C" void kernel_launch(void* const* d_in, const int* in_sizes, int n_in,
                              void* d_out, int out_size, void* d_ws,
                              size_t ws_size, hipStream_t stream) {
  const float* x = (const float*)d_in[0];   // (128,400,100) fp32
  const int* seg = (const int*)d_in[1];     // (128,2) int32
  float* out = (float*)d_out;               // (128,400,16) fp32
  (void)d_ws; (void)ws_size;

  dim3 grid(4, Bb);                         // 512 blocks, 8 waves each
  TemporalPooling_mfma_kernel<<<grid, 512, 0, stream>>>(x, seg, out);
}